// Round 2
// baseline (346.599 us; speedup 1.0000x reference)
//
#include <hip/hip_runtime.h>
#include <math.h>

#define N_PTS     131072
#define G_NUMS    30
#define G_SIZE    100
#define PT_STRIDE (N_PTS / G_NUMS)   // 4369
#define TPB       1024
#define NWAVES    (TPB / 64)         // 16
#define BINS      4096
#define JB        (BINS / TPB)       // 4 bins per thread
#define SHIFT     20
#define SAMPLE_GRPS 1024             // first 4096 points as iid sample
#define RANK_CUT  32                 // 32nd-smallest sample -> tau (P(fail) ~ 1e-25)
#define CAP       3072               // survivor capacity (~11 sigma above mean ~1024)
#define TIE_CAP   64

struct KSmem {
    union {
        unsigned hist[BINS];         // 16 KB
        struct {                     // finalize overlay (last block only)
            float gm[256][3];
            float dir[256][3];
            float pe[NWAVES];
            float ps[NWAVES];
        } fin;
    };
    unsigned wsum[NWAVES];
    unsigned T;
    int ns, nd, nt;
    int lastblk;
    unsigned u[CAP];
    int idx[CAP];
    float px[CAP], py[CAP], pz[CAP]; // survivor coords stay in LDS
    int sel[G_SIZE];                 // positions into survivor arrays
    unsigned tu[TIE_CAP];
    int ti[TIE_CAP];                 // positions
    float acc[3], cov[6], q[3];
    unsigned tau0, maxu, r1;
    float delta2;
};

__device__ __forceinline__ float dist2f(float px, float py, float pz,
                                        float qx, float qy, float qz) {
    float dx = px - qx, dy = py - qy, dz = pz - qz;
    return fmaf(dx, dx, fmaf(dy, dy, dz * dz));
}

// Find smallest bin T such that cumulative count through T >= rank.
__device__ __forceinline__ unsigned find_bin(KSmem& sm, unsigned rank,
                                             int tid, int lane, int wid) {
    unsigned hv[JB], csum = 0;
#pragma unroll
    for (int j = 0; j < JB; j++) { hv[j] = sm.hist[tid * JB + j]; csum += hv[j]; }
    unsigned inc = csum;
#pragma unroll
    for (int off = 1; off < 64; off <<= 1) {
        unsigned n = __shfl_up(inc, off);
        if (lane >= off) inc += n;
    }
    __syncthreads();                  // protect wsum reuse across calls
    if (lane == 63) sm.wsum[wid] = inc;
    __syncthreads();
    unsigned base = 0;
    for (int w = 0; w < wid; w++) base += sm.wsum[w];
    unsigned c = base + inc - csum;   // exclusive prefix before this thread's chunk
#pragma unroll
    for (int j = 0; j < JB; j++) {
        if (c < rank && c + hv[j] >= rank) sm.T = (unsigned)(tid * JB + j);
        c += hv[j];
    }
    __syncthreads();
    return sm.T;
}

// Exact 100-NN of (qx,qy,qz): sample tau (AoS) -> [optional wait] -> filter scan
// (SoA or AoS) with LDS coord stash -> fine histogram select.
// Leaves: sm.sel[0..99] survivor POSITIONS, sm.ns raw count, sm.u/idx/px/py/pz.
template<bool SOA>
__device__ void knn_select(const float4* __restrict__ P4,
                           const float4* __restrict__ X4,
                           const float4* __restrict__ Y4,
                           const float4* __restrict__ Z4,
                           KSmem& sm, float qx, float qy, float qz,
                           int tid, int lane, int wid, bool save_tau,
                           unsigned* tc_wait /* nullptr = no wait */) {
    for (int j = tid; j < BINS; j += TPB) sm.hist[j] = 0u;
    if (tid == 0) { sm.ns = 0; sm.nd = 0; sm.nt = 0; sm.T = 0u; }
    __syncthreads();

    // ---- sample scan (AoS; always valid, overlaps other blocks' transposes) ----
    for (int grp = tid; grp < SAMPLE_GRPS; grp += TPB) {
        float4 f0 = P4[3 * grp + 0];
        float4 f1 = P4[3 * grp + 1];
        float4 f2 = P4[3 * grp + 2];
        atomicAdd(&sm.hist[__float_as_uint(dist2f(f0.x, f0.y, f0.z, qx, qy, qz)) >> SHIFT], 1u);
        atomicAdd(&sm.hist[__float_as_uint(dist2f(f0.w, f1.x, f1.y, qx, qy, qz)) >> SHIFT], 1u);
        atomicAdd(&sm.hist[__float_as_uint(dist2f(f1.z, f1.w, f2.x, qx, qy, qz)) >> SHIFT], 1u);
        atomicAdd(&sm.hist[__float_as_uint(dist2f(f2.y, f2.z, f2.w, qx, qy, qz)) >> SHIFT], 1u);
    }
    __syncthreads();
    unsigned Tc = find_bin(sm, RANK_CUT, tid, lane, wid);
    const unsigned tau = (Tc >= BINS - 1) ? 0xFFFFFFFFu : ((Tc + 1) << SHIFT);
    if (save_tau && tid == 0) sm.tau0 = tau;
    for (int j = tid; j < BINS; j += TPB) sm.hist[j] = 0u;   // re-zero for fine pass
    if (tc_wait && tid == 0) {       // wait for this batch's SoA to be complete
        while (__hip_atomic_load(tc_wait, __ATOMIC_ACQUIRE, __HIP_MEMORY_SCOPE_AGENT)
               < (unsigned)G_NUMS)
            __builtin_amdgcn_s_sleep(2);
    }
    __syncthreads();
    if (tc_wait) __threadfence();    // acquire: invalidate caches before SoA reads

    // ---- full scan: pure filter, rare compaction (hit rate ~1/128) ----
    if constexpr (SOA) {
#pragma unroll 4
        for (int i = tid; i < N_PTS / 4; i += TPB) {
            float4 xv = X4[i], yv = Y4[i], zv = Z4[i];
            unsigned u0 = __float_as_uint(dist2f(xv.x, yv.x, zv.x, qx, qy, qz));
            unsigned u1 = __float_as_uint(dist2f(xv.y, yv.y, zv.y, qx, qy, qz));
            unsigned u2 = __float_as_uint(dist2f(xv.z, yv.z, zv.z, qx, qy, qz));
            unsigned u3 = __float_as_uint(dist2f(xv.w, yv.w, zv.w, qx, qy, qz));
            int i0 = i * 4;
            if (u0 < tau) { int p = atomicAdd(&sm.ns, 1); if (p < CAP) { sm.u[p] = u0; sm.idx[p] = i0;     sm.px[p] = xv.x; sm.py[p] = yv.x; sm.pz[p] = zv.x; } }
            if (u1 < tau) { int p = atomicAdd(&sm.ns, 1); if (p < CAP) { sm.u[p] = u1; sm.idx[p] = i0 + 1; sm.px[p] = xv.y; sm.py[p] = yv.y; sm.pz[p] = zv.y; } }
            if (u2 < tau) { int p = atomicAdd(&sm.ns, 1); if (p < CAP) { sm.u[p] = u2; sm.idx[p] = i0 + 2; sm.px[p] = xv.z; sm.py[p] = yv.z; sm.pz[p] = zv.z; } }
            if (u3 < tau) { int p = atomicAdd(&sm.ns, 1); if (p < CAP) { sm.u[p] = u3; sm.idx[p] = i0 + 3; sm.px[p] = xv.w; sm.py[p] = yv.w; sm.pz[p] = zv.w; } }
        }
    } else {
#pragma unroll 4
        for (int grp = tid; grp < N_PTS / 4; grp += TPB) {
            float4 f0 = P4[3 * grp + 0];
            float4 f1 = P4[3 * grp + 1];
            float4 f2 = P4[3 * grp + 2];
            unsigned u0 = __float_as_uint(dist2f(f0.x, f0.y, f0.z, qx, qy, qz));
            unsigned u1 = __float_as_uint(dist2f(f0.w, f1.x, f1.y, qx, qy, qz));
            unsigned u2 = __float_as_uint(dist2f(f1.z, f1.w, f2.x, qx, qy, qz));
            unsigned u3 = __float_as_uint(dist2f(f2.y, f2.z, f2.w, qx, qy, qz));
            int i0 = grp * 4;
            if (u0 < tau) { int p = atomicAdd(&sm.ns, 1); if (p < CAP) { sm.u[p] = u0; sm.idx[p] = i0;     sm.px[p] = f0.x; sm.py[p] = f0.y; sm.pz[p] = f0.z; } }
            if (u1 < tau) { int p = atomicAdd(&sm.ns, 1); if (p < CAP) { sm.u[p] = u1; sm.idx[p] = i0 + 1; sm.px[p] = f0.w; sm.py[p] = f1.x; sm.pz[p] = f1.y; } }
            if (u2 < tau) { int p = atomicAdd(&sm.ns, 1); if (p < CAP) { sm.u[p] = u2; sm.idx[p] = i0 + 2; sm.px[p] = f1.z; sm.py[p] = f1.w; sm.pz[p] = f2.x; } }
            if (u3 < tau) { int p = atomicAdd(&sm.ns, 1); if (p < CAP) { sm.u[p] = u3; sm.idx[p] = i0 + 3; sm.px[p] = f2.y; sm.py[p] = f2.z; sm.pz[p] = f2.w; } }
        }
    }
    __syncthreads();
    int S = sm.ns; if (S > CAP) S = CAP;

    // ---- fine histogram over survivors: exact rank-100 bin ----
    unsigned hb = 32u - (unsigned)__clz(tau - 1u);
    unsigned s2 = hb > 12u ? hb - 12u : 0u;
    for (int i = tid; i < S; i += TPB) atomicAdd(&sm.hist[sm.u[i] >> s2], 1u);
    __syncthreads();
    unsigned T2 = find_bin(sm, G_SIZE, tid, lane, wid);
    const unsigned lo = T2 << s2;

    // ---- collect definite + ties (store positions) ----
    for (int i = tid; i < S; i += TPB) {
        unsigned uu = sm.u[i];
        if (uu < lo) {
            int p = atomicAdd(&sm.nd, 1);
            if (p < G_SIZE) sm.sel[p] = i;
        } else if ((uu >> s2) == T2) {
            int p = atomicAdd(&sm.nt, 1);
            if (p < TIE_CAP) { sm.tu[p] = uu; sm.ti[p] = i; }
        }
    }
    __syncthreads();
    if (tid == 0) {
        int nd = sm.nd; if (nd > G_SIZE) nd = G_SIZE;
        int need = G_SIZE - nd;
        int ec = sm.nt; if (ec > TIE_CAP) ec = TIE_CAP;
        for (int a = 0; a < need && a < ec; ++a) {
            int best = a;
            for (int j = a + 1; j < ec; ++j)
                if (sm.tu[j] < sm.tu[best] ||
                    (sm.tu[j] == sm.tu[best] && sm.idx[sm.ti[j]] < sm.idx[sm.ti[best]])) best = j;
            unsigned tub = sm.tu[best]; sm.tu[best] = sm.tu[a]; sm.tu[a] = tub;
            int tib = sm.ti[best]; sm.ti[best] = sm.ti[a]; sm.ti[a] = tib;
            sm.sel[nd + a] = sm.ti[a];
        }
    }
    __syncthreads();
}

// ---- 3x3 symmetric eigensolve (Jacobi, double) ----
__device__ void eig3(const float cf[6], double lam_out[3], double dir_out[3]) {
    double a[3][3], v[3][3];
    a[0][0] = cf[0]; a[0][1] = cf[1]; a[0][2] = cf[2];
    a[1][0] = cf[1]; a[1][1] = cf[3]; a[1][2] = cf[4];
    a[2][0] = cf[2]; a[2][1] = cf[4]; a[2][2] = cf[5];
    for (int i = 0; i < 3; i++)
        for (int j = 0; j < 3; j++) v[i][j] = (i == j) ? 1.0 : 0.0;

    for (int sweep = 0; sweep < 12; sweep++) {
        double off = a[0][1] * a[0][1] + a[0][2] * a[0][2] + a[1][2] * a[1][2];
        if (off == 0.0) break;
        for (int p = 0; p < 2; p++) {
            for (int q = p + 1; q < 3; q++) {
                double apq = a[p][q];
                if (apq == 0.0) continue;
                double app = a[p][p], aqq = a[q][q];
                double theta = (aqq - app) / (2.0 * apq);
                double t = (theta >= 0.0 ? 1.0 : -1.0) /
                           (fabs(theta) + sqrt(theta * theta + 1.0));
                double c = 1.0 / sqrt(t * t + 1.0);
                double s = t * c;
                a[p][p] = app - t * apq;
                a[q][q] = aqq + t * apq;
                a[p][q] = 0.0; a[q][p] = 0.0;
                for (int r = 0; r < 3; r++) {
                    if (r == p || r == q) continue;
                    double arp = a[r][p], arq = a[r][q];
                    a[r][p] = c * arp - s * arq; a[p][r] = a[r][p];
                    a[r][q] = s * arp + c * arq; a[q][r] = a[r][q];
                }
                for (int r = 0; r < 3; r++) {
                    double vrp = v[r][p], vrq = v[r][q];
                    v[r][p] = c * vrp - s * vrq;
                    v[r][q] = s * vrp + c * vrq;
                }
            }
        }
    }
    double l0 = a[0][0], l1 = a[1][1], l2 = a[2][2];
    int i0 = 0, i1 = 1, i2 = 2;
    if (l0 > l1) { double t = l0; l0 = l1; l1 = t; int ti = i0; i0 = i1; i1 = ti; }
    if (l1 > l2) { double t = l1; l1 = l2; l2 = t; int ti = i1; i1 = i2; i2 = ti; }
    if (l0 > l1) { double t = l0; l0 = l1; l1 = t; int ti = i0; i0 = i1; i1 = ti; }
    lam_out[0] = l0; lam_out[1] = l1; lam_out[2] = l2;
    dir_out[0] = v[0][i2]; dir_out[1] = v[1][i2]; dir_out[2] = v[2][i2];
}

// Single fused kernel. One block per (batch, group):
//   transpose own slice -> release-arrive tc[b] -> sample scan (AoS, overlapped)
//   -> acquire-wait tc[b]==30 -> SoA full scan/select -> mean -> certified
//   survivor-reuse phase 1 (fallback: full scan) -> cov -> done-counter;
//   last block runs finalize inline.
template<bool SOA>
__global__ __launch_bounds__(TPB)
void fused_all_kernel(const float* __restrict__ pts,
                      float* __restrict__ sx, float* __restrict__ sy,
                      float* __restrict__ sz,
                      float* __restrict__ gmeans, float* __restrict__ covs,
                      float* __restrict__ out,
                      unsigned* __restrict__ syncw,  // [0..B-1]=tc, [B]=done
                      int B, int nblk) {
    __shared__ KSmem sm;

    const int blk = blockIdx.x;
    const int b = blk % B;           // batch-per-XCD swizzle (L2 locality)
    const int g = blk / B;
    const int gi = b * G_NUMS + g;   // b-major for finalize
    const float* __restrict__ P = pts + (size_t)b * (N_PTS * 3);
    const float4* __restrict__ P4 = (const float4*)P;
    float* BX = nullptr; float* BY = nullptr; float* BZ = nullptr;
    const float4* X4 = nullptr; const float4* Y4 = nullptr; const float4* Z4 = nullptr;
    if constexpr (SOA) {
        BX = sx + (size_t)b * N_PTS;
        BY = sy + (size_t)b * N_PTS;
        BZ = sz + (size_t)b * N_PTS;
        X4 = (const float4*)BX; Y4 = (const float4*)BY; Z4 = (const float4*)BZ;
    }
    const int tid = threadIdx.x;
    const int lane = tid & 63, wid = tid >> 6;

    if (tid == 0) {
        const float* qp = P + (size_t)g * PT_STRIDE * 3;
        sm.q[0] = qp[0]; sm.q[1] = qp[1]; sm.q[2] = qp[2];
    }
    if (tid < 3) sm.acc[tid] = 0.f;
    if (tid < 6) sm.cov[tid] = 0.f;

    // ---- transpose my 1/30 slice of batch b into SoA ----
    if constexpr (SOA) {
        const int per = (N_PTS / 4 + G_NUMS - 1) / G_NUMS;   // 1093 float4-groups
        int t0 = g * per;
        int t1 = t0 + per; if (t1 > N_PTS / 4) t1 = N_PTS / 4;
        for (int t = t0 + tid; t < t1; t += TPB) {
            float4 f0 = P4[3 * t + 0];
            float4 f1 = P4[3 * t + 1];
            float4 f2 = P4[3 * t + 2];
            ((float4*)BX)[t] = make_float4(f0.x, f0.w, f1.z, f2.y);
            ((float4*)BY)[t] = make_float4(f0.y, f1.x, f1.w, f2.z);
            ((float4*)BZ)[t] = make_float4(f0.z, f1.y, f2.x, f2.w);
        }
        __threadfence();             // release: push SoA writes device-visible
    }
    __syncthreads();
    if constexpr (SOA) {
        if (tid == 0)
            __hip_atomic_fetch_add(&syncw[b], 1u, __ATOMIC_RELEASE,
                                   __HIP_MEMORY_SCOPE_AGENT);
    }
    const float qx = sm.q[0], qy = sm.q[1], qz = sm.q[2];

    // ================= phase 0 =================
    knn_select<SOA>(P4, X4, Y4, Z4, sm, qx, qy, qz, tid, lane, wid, true,
                    SOA ? &syncw[b] : nullptr);

    if (tid < G_SIZE) {
        int p = sm.sel[tid];
        atomicAdd(&sm.acc[0], sm.px[p]);
        atomicAdd(&sm.acc[1], sm.py[p]);
        atomicAdd(&sm.acc[2], sm.pz[p]);
    }
    __syncthreads();
    const int S0 = sm.ns;            // raw phase-0 survivor count
    if (tid == 0) {
        float mx = sm.acc[0] * (1.0f / G_SIZE);
        float my = sm.acc[1] * (1.0f / G_SIZE);
        float mz = sm.acc[2] * (1.0f / G_SIZE);
        gmeans[(size_t)gi * 3 + 0] = mx;
        gmeans[(size_t)gi * 3 + 1] = my;
        gmeans[(size_t)gi * 3 + 2] = mz;
        float dx = mx - qx, dy = my - qy, dz = mz - qz;
        sm.delta2 = fmaf(dx, dx, fmaf(dy, dy, dz * dz));
        sm.q[0] = mx; sm.q[1] = my; sm.q[2] = mz;
        sm.acc[0] = 0.f; sm.acc[1] = 0.f; sm.acc[2] = 0.f;
        sm.maxu = 0u; sm.r1 = 0u; sm.T = 0u;
        sm.nd = 0; sm.nt = 0;
        sm.lastblk = 0;
    }
    __shared__ int s_fastok;
    if (tid == 0) s_fastok = 0;
    __syncthreads();
    const float q1x = sm.q[0], q1y = sm.q[1], q1z = sm.q[2];

    // ============ phase 1 fast path: certified survivor reuse (LDS coords) ============
    const bool attempt = (S0 >= G_SIZE) && (S0 <= CAP);  // complete survivor set
    if (attempt) {
        for (int j = tid; j < BINS; j += TPB) sm.hist[j] = 0u;
        for (int i = tid; i < S0; i += TPB) {
            unsigned uu = __float_as_uint(
                dist2f(sm.px[i], sm.py[i], sm.pz[i], q1x, q1y, q1z));
            sm.u[i] = uu;
            atomicMax(&sm.maxu, uu);
        }
        __syncthreads();
        unsigned maxu = sm.maxu;
        unsigned hb = (maxu == 0u) ? 0u : (32u - (unsigned)__clz(maxu));
        unsigned s3 = hb > 12u ? hb - 12u : 0u;
        for (int i = tid; i < S0; i += TPB) atomicAdd(&sm.hist[sm.u[i] >> s3], 1u);
        __syncthreads();
        unsigned T2 = find_bin(sm, G_SIZE, tid, lane, wid);
        const unsigned lo = T2 << s3;
        for (int i = tid; i < S0; i += TPB) {
            unsigned uu = sm.u[i];
            if (uu < lo) {
                int p = atomicAdd(&sm.nd, 1);
                if (p < G_SIZE) sm.sel[p] = i;
            } else if ((uu >> s3) == T2) {
                int p = atomicAdd(&sm.nt, 1);
                if (p < TIE_CAP) { sm.tu[p] = uu; sm.ti[p] = i; }
            }
        }
        __syncthreads();
        if (tid == 0) {
            int ok = 1;
            int nd = sm.nd; if (nd > G_SIZE) { nd = G_SIZE; ok = 0; }
            int need = G_SIZE - nd;
            if (sm.nt > TIE_CAP) ok = 0;
            int ec = sm.nt; if (ec > TIE_CAP) ec = TIE_CAP;
            if (need > ec) ok = 0;
            for (int a = 0; a < need && a < ec; ++a) {
                int best = a;
                for (int j = a + 1; j < ec; ++j)
                    if (sm.tu[j] < sm.tu[best] ||
                        (sm.tu[j] == sm.tu[best] && sm.idx[sm.ti[j]] < sm.idx[sm.ti[best]])) best = j;
                unsigned tub = sm.tu[best]; sm.tu[best] = sm.tu[a]; sm.tu[a] = tub;
                int tib = sm.ti[best]; sm.ti[best] = sm.ti[a]; sm.ti[a] = tib;
                sm.sel[nd + a] = sm.ti[a];
            }
            s_fastok = ok;
        }
        __syncthreads();
        if (s_fastok) {
            if (tid < G_SIZE) atomicMax(&sm.r1, sm.u[sm.sel[tid]]);
            __syncthreads();
            if (tid == 0) {
                // certificate: every non-survivor p has d0(p) >= R0, so
                // d1(p) >= R0 - delta; exact iff R0 - delta > r1 (with fp margin)
                double R0 = sqrt((double)__uint_as_float(sm.tau0));
                double dl = sqrt((double)sm.delta2);
                double r1 = sqrt((double)__uint_as_float(sm.r1));
                if (!((R0 - dl) > r1 * 1.0001 + 1e-7)) s_fastok = 0;
            }
            __syncthreads();
        }
    }

    // ============ phase 1 fallback: exact full scan (rare) ============
    if (!attempt || !s_fastok) {
        knn_select<SOA>(P4, X4, Y4, Z4, sm, q1x, q1y, q1z, tid, lane, wid, false,
                        nullptr);
    }

    // ============ mean / covariance over the exact 100 (LDS coords) ============
    float px = 0.f, py = 0.f, pz = 0.f;
    if (tid < G_SIZE) {
        int p = sm.sel[tid];
        px = sm.px[p]; py = sm.py[p]; pz = sm.pz[p];
        atomicAdd(&sm.acc[0], px);
        atomicAdd(&sm.acc[1], py);
        atomicAdd(&sm.acc[2], pz);
    }
    __syncthreads();
    float mx = sm.acc[0] * (1.0f / G_SIZE);
    float my = sm.acc[1] * (1.0f / G_SIZE);
    float mz = sm.acc[2] * (1.0f / G_SIZE);
    if (tid < G_SIZE) {
        float x = px - mx, y = py - my, z = pz - mz;
        atomicAdd(&sm.cov[0], x * x);
        atomicAdd(&sm.cov[1], x * y);
        atomicAdd(&sm.cov[2], x * z);
        atomicAdd(&sm.cov[3], y * y);
        atomicAdd(&sm.cov[4], y * z);
        atomicAdd(&sm.cov[5], z * z);
    }
    __syncthreads();
    if (tid < 6) covs[(size_t)gi * 6 + tid] = sm.cov[tid] * (1.0f / G_SIZE);

    // ============ last-block-done election ============
    __threadfence();                 // release: gmeans/covs device-visible
    __syncthreads();
    if (tid == 0) {
        unsigned old = __hip_atomic_fetch_add(&syncw[B], 1u, __ATOMIC_ACQ_REL,
                                              __HIP_MEMORY_SCOPE_AGENT);
        sm.lastblk = (old == (unsigned)(nblk - 1)) ? 1 : 0;
    }
    __syncthreads();
    if (!sm.lastblk) return;

    // ============ finalize (runs once, in the last block) ============
    __threadfence();                 // acquire: see all blocks' gmeans/covs
    const int NG = nblk;             // 240
    float et = 0.f;
    if (tid < NG) {
        float cf[6];
#pragma unroll
        for (int j = 0; j < 6; j++) cf[j] = covs[tid * 6 + j];
        double lam[3], dir[3];
        eig3(cf, lam, dir);
        double denom = lam[0] + lam[1] + lam[2] + 1e-9;
        et = (float)((lam[2] - lam[1]) / denom);
        sm.fin.dir[tid][0] = (float)dir[0];
        sm.fin.dir[tid][1] = (float)dir[1];
        sm.fin.dir[tid][2] = (float)dir[2];
        sm.fin.gm[tid][0] = gmeans[tid * 3 + 0];
        sm.fin.gm[tid][1] = gmeans[tid * 3 + 1];
        sm.fin.gm[tid][2] = gmeans[tid * 3 + 2];
    }
    __syncthreads();

    float st = 0.f;
    if (tid < NG) {
        int bb = tid / G_NUMS, gg0 = tid % G_NUMS;
        float gx = sm.fin.gm[tid][0], gy = sm.fin.gm[tid][1], gz = sm.fin.gm[tid][2];
        float bd = 3.4e38f; int bj = 0;
        for (int gg = 0; gg < G_NUMS; gg++) {
            if (gg == gg0) continue;
            int o = bb * G_NUMS + gg;
            float dx = gx - sm.fin.gm[o][0];
            float dy = gy - sm.fin.gm[o][1];
            float dz = gz - sm.fin.gm[o][2];
            float d = dx * dx + dy * dy + dz * dz;
            if (d < bd) { bd = d; bj = gg; }
        }
        int o = bb * G_NUMS + bj;
        float cosv = sm.fin.dir[tid][0] * sm.fin.dir[o][0] +
                     sm.fin.dir[tid][1] * sm.fin.dir[o][1] +
                     sm.fin.dir[tid][2] * sm.fin.dir[o][2];
        st = 1.f - cosv * cosv;
    }

    float e = et, s2 = st;
#pragma unroll
    for (int off = 32; off > 0; off >>= 1) {
        e += __shfl_down(e, off);
        s2 += __shfl_down(s2, off);
    }
    if (lane == 0) { sm.fin.pe[wid] = e; sm.fin.ps[wid] = s2; }
    __syncthreads();
    if (tid == 0) {
        float se = 0.f, ss = 0.f;
        for (int w = 0; w < NWAVES; w++) { se += sm.fin.pe[w]; ss += sm.fin.ps[w]; }
        out[0] = -se / (float)B + ss / (float)NG;
    }
}

extern "C" void kernel_launch(void* const* d_in, const int* in_sizes, int n_in,
                              void* d_out, int out_size, void* d_ws, size_t ws_size,
                              hipStream_t stream) {
    const float* pts = (const float*)d_in[0];
    float* out = (float*)d_out;
    float* ws = (float*)d_ws;
    int B = in_sizes[0] / (N_PTS * 3);   // 8
    int nblk = B * G_NUMS;               // 240

    float* gmeans = ws;                              // B*G_NUMS*3 floats
    float* covs = ws + (size_t)B * G_NUMS * 3;       // B*G_NUMS*6 floats
    const size_t base_floats = (size_t)B * G_NUMS * 9;
    unsigned* syncw = (unsigned*)(ws + base_floats); // 16 uints (tc[B] + done)
    float* soa = ws + base_floats + 16;
    const size_t soa_floats = 3 * (size_t)B * N_PTS;
    const bool use_soa = ws_size >= (base_floats + 16 + soa_floats) * sizeof(float);

    hipMemsetAsync(syncw, 0, 64, stream);            // zero tc[] + done

    dim3 grid(nblk);
    if (use_soa) {
        float* sx = soa;
        float* sy = sx + (size_t)B * N_PTS;
        float* sz = sy + (size_t)B * N_PTS;
        fused_all_kernel<true><<<grid, TPB, 0, stream>>>(
            pts, sx, sy, sz, gmeans, covs, out, syncw, B, nblk);
    } else {
        fused_all_kernel<false><<<grid, TPB, 0, stream>>>(
            pts, nullptr, nullptr, nullptr, gmeans, covs, out, syncw, B, nblk);
    }
}

// Round 5
// 140.067 us; speedup vs baseline: 2.4745x; 2.4745x over previous
//
#include <hip/hip_runtime.h>
#include <math.h>

#define N_PTS     131072
#define G_NUMS    30
#define G_SIZE    100
#define PT_STRIDE (N_PTS / G_NUMS)   // 4369
#define TPB       1024
#define NWAVES    (TPB / 64)         // 16
#define BINS      4096
#define JB        (BINS / TPB)       // 4 bins per thread
#define SHIFT     20
#define SAMPLE_GRPS 1024             // first 4096 points as iid sample
#define RANK_CUT  32                 // 32nd-smallest sample -> tau (P(fail) ~ 1e-25)
#define CAP       3072               // survivor capacity (~11 sigma above mean ~1024)
#define TIE_CAP   64

struct KSmem {
    union {
        unsigned hist[BINS];         // 16 KB
        struct {                     // finalize overlay (last block only)
            float gm[256][3];
            float dir[256][3];
            float pe[NWAVES];
            float ps[NWAVES];
        } fin;
    };
    unsigned wsum[NWAVES];
    unsigned T;
    int ns, nd, nt;
    unsigned u[CAP];
    int idx[CAP];
    float px[CAP], py[CAP], pz[CAP]; // survivor coords stay in LDS
    int sel[G_SIZE];                 // positions into survivor arrays
    unsigned tu[TIE_CAP];
    int ti[TIE_CAP];                 // positions
    float acc[3], cov[6], q[3];
    unsigned tau0, maxu, r1;
    float delta2;
};

__device__ __forceinline__ float dist2f(float px, float py, float pz,
                                        float qx, float qy, float qz) {
    float dx = px - qx, dy = py - qy, dz = pz - qz;
    return fmaf(dx, dx, fmaf(dy, dy, dz * dz));
}

// Find smallest bin T such that cumulative count through T >= rank.
__device__ __forceinline__ unsigned find_bin(KSmem& sm, unsigned rank,
                                             int tid, int lane, int wid) {
    unsigned hv[JB], csum = 0;
#pragma unroll
    for (int j = 0; j < JB; j++) { hv[j] = sm.hist[tid * JB + j]; csum += hv[j]; }
    unsigned inc = csum;
#pragma unroll
    for (int off = 1; off < 64; off <<= 1) {
        unsigned n = __shfl_up(inc, off);
        if (lane >= off) inc += n;
    }
    __syncthreads();                  // protect wsum reuse across calls
    if (lane == 63) sm.wsum[wid] = inc;
    __syncthreads();
    unsigned base = 0;
    for (int w = 0; w < wid; w++) base += sm.wsum[w];
    unsigned c = base + inc - csum;   // exclusive prefix before this thread's chunk
#pragma unroll
    for (int j = 0; j < JB; j++) {
        if (c < rank && c + hv[j] >= rank) sm.T = (unsigned)(tid * JB + j);
        c += hv[j];
    }
    __syncthreads();
    return sm.T;
}

// Distance + filter + LDS survivor stash for one float4-group (4 points).
__device__ __forceinline__ void push4(KSmem& sm, const float4& xv, const float4& yv,
                                      const float4& zv, int i, unsigned tau,
                                      float qx, float qy, float qz) {
    unsigned u0 = __float_as_uint(dist2f(xv.x, yv.x, zv.x, qx, qy, qz));
    unsigned u1 = __float_as_uint(dist2f(xv.y, yv.y, zv.y, qx, qy, qz));
    unsigned u2 = __float_as_uint(dist2f(xv.z, yv.z, zv.z, qx, qy, qz));
    unsigned u3 = __float_as_uint(dist2f(xv.w, yv.w, zv.w, qx, qy, qz));
    int i0 = i * 4;
    if (u0 < tau) { int p = atomicAdd(&sm.ns, 1); if (p < CAP) { sm.u[p] = u0; sm.idx[p] = i0;     sm.px[p] = xv.x; sm.py[p] = yv.x; sm.pz[p] = zv.x; } }
    if (u1 < tau) { int p = atomicAdd(&sm.ns, 1); if (p < CAP) { sm.u[p] = u1; sm.idx[p] = i0 + 1; sm.px[p] = xv.y; sm.py[p] = yv.y; sm.pz[p] = zv.y; } }
    if (u2 < tau) { int p = atomicAdd(&sm.ns, 1); if (p < CAP) { sm.u[p] = u2; sm.idx[p] = i0 + 2; sm.px[p] = xv.z; sm.py[p] = yv.z; sm.pz[p] = zv.z; } }
    if (u3 < tau) { int p = atomicAdd(&sm.ns, 1); if (p < CAP) { sm.u[p] = u3; sm.idx[p] = i0 + 3; sm.px[p] = xv.w; sm.py[p] = yv.w; sm.pz[p] = zv.w; } }
}

// Exact 100-NN of (qx,qy,qz): sample tau -> filter scan (batched loads for MLP)
// with LDS coord stash -> fine histogram select.
// Leaves: sm.sel[0..99] survivor POSITIONS, sm.ns raw count, sm.u/idx/px/py/pz.
template<bool SOA>
__device__ void knn_select(const float4* __restrict__ P4,
                           const float4* __restrict__ X4,
                           const float4* __restrict__ Y4,
                           const float4* __restrict__ Z4,
                           KSmem& sm, float qx, float qy, float qz,
                           int tid, int lane, int wid, bool save_tau) {
    for (int j = tid; j < BINS; j += TPB) sm.hist[j] = 0u;
    if (tid == 0) { sm.ns = 0; sm.nd = 0; sm.nt = 0; sm.T = 0u; }
    __syncthreads();

    // ---- sample scan: 4096 distances -> coarse histogram ----
    if constexpr (SOA) {
        for (int i = tid; i < SAMPLE_GRPS; i += TPB) {
            float4 xv = X4[i], yv = Y4[i], zv = Z4[i];
            atomicAdd(&sm.hist[__float_as_uint(dist2f(xv.x, yv.x, zv.x, qx, qy, qz)) >> SHIFT], 1u);
            atomicAdd(&sm.hist[__float_as_uint(dist2f(xv.y, yv.y, zv.y, qx, qy, qz)) >> SHIFT], 1u);
            atomicAdd(&sm.hist[__float_as_uint(dist2f(xv.z, yv.z, zv.z, qx, qy, qz)) >> SHIFT], 1u);
            atomicAdd(&sm.hist[__float_as_uint(dist2f(xv.w, yv.w, zv.w, qx, qy, qz)) >> SHIFT], 1u);
        }
    } else {
        for (int grp = tid; grp < SAMPLE_GRPS; grp += TPB) {
            float4 f0 = P4[3 * grp + 0];
            float4 f1 = P4[3 * grp + 1];
            float4 f2 = P4[3 * grp + 2];
            atomicAdd(&sm.hist[__float_as_uint(dist2f(f0.x, f0.y, f0.z, qx, qy, qz)) >> SHIFT], 1u);
            atomicAdd(&sm.hist[__float_as_uint(dist2f(f0.w, f1.x, f1.y, qx, qy, qz)) >> SHIFT], 1u);
            atomicAdd(&sm.hist[__float_as_uint(dist2f(f1.z, f1.w, f2.x, qx, qy, qz)) >> SHIFT], 1u);
            atomicAdd(&sm.hist[__float_as_uint(dist2f(f2.y, f2.z, f2.w, qx, qy, qz)) >> SHIFT], 1u);
        }
    }
    __syncthreads();
    unsigned Tc = find_bin(sm, RANK_CUT, tid, lane, wid);
    const unsigned tau = (Tc >= BINS - 1) ? 0xFFFFFFFFu : ((Tc + 1) << SHIFT);
    if (save_tau && tid == 0) sm.tau0 = tau;
    for (int j = tid; j < BINS; j += TPB) sm.hist[j] = 0u;   // re-zero for fine pass
    __syncthreads();

    // ---- full scan: 12 loads batched back-to-back before any use (MLP),
    //      then pure filter with rare compaction (hit rate ~1/128) ----
    if constexpr (SOA) {
        for (int base = 0; base < N_PTS / 4; base += TPB * 4) {   // 8 iterations
            int ia = base + tid, ib = ia + TPB, ic = ib + TPB, id_ = ic + TPB;
            float4 xa = X4[ia], ya = Y4[ia], za = Z4[ia];
            float4 xb = X4[ib], yb = Y4[ib], zb = Z4[ib];
            float4 xc = X4[ic], yc = Y4[ic], zc = Z4[ic];
            float4 xd = X4[id_], yd = Y4[id_], zd = Z4[id_];
            push4(sm, xa, ya, za, ia, tau, qx, qy, qz);
            push4(sm, xb, yb, zb, ib, tau, qx, qy, qz);
            push4(sm, xc, yc, zc, ic, tau, qx, qy, qz);
            push4(sm, xd, yd, zd, id_, tau, qx, qy, qz);
        }
    } else {
#pragma unroll 4
        for (int grp = tid; grp < N_PTS / 4; grp += TPB) {
            float4 f0 = P4[3 * grp + 0];
            float4 f1 = P4[3 * grp + 1];
            float4 f2 = P4[3 * grp + 2];
            float4 xv = make_float4(f0.x, f0.w, f1.z, f2.y);
            float4 yv = make_float4(f0.y, f1.x, f1.w, f2.z);
            float4 zv = make_float4(f0.z, f1.y, f2.x, f2.w);
            push4(sm, xv, yv, zv, grp, tau, qx, qy, qz);
        }
    }
    __syncthreads();
    int S = sm.ns; if (S > CAP) S = CAP;

    // ---- fine histogram over survivors: exact rank-100 bin ----
    unsigned hb = 32u - (unsigned)__clz(tau - 1u);
    unsigned s2 = hb > 12u ? hb - 12u : 0u;
    for (int i = tid; i < S; i += TPB) atomicAdd(&sm.hist[sm.u[i] >> s2], 1u);
    __syncthreads();
    unsigned T2 = find_bin(sm, G_SIZE, tid, lane, wid);
    const unsigned lo = T2 << s2;

    // ---- collect definite + ties (store positions) ----
    for (int i = tid; i < S; i += TPB) {
        unsigned uu = sm.u[i];
        if (uu < lo) {
            int p = atomicAdd(&sm.nd, 1);
            if (p < G_SIZE) sm.sel[p] = i;
        } else if ((uu >> s2) == T2) {
            int p = atomicAdd(&sm.nt, 1);
            if (p < TIE_CAP) { sm.tu[p] = uu; sm.ti[p] = i; }
        }
    }
    __syncthreads();
    if (tid == 0) {
        int nd = sm.nd; if (nd > G_SIZE) nd = G_SIZE;
        int need = G_SIZE - nd;
        int ec = sm.nt; if (ec > TIE_CAP) ec = TIE_CAP;
        for (int a = 0; a < need && a < ec; ++a) {
            int best = a;
            for (int j = a + 1; j < ec; ++j)
                if (sm.tu[j] < sm.tu[best] ||
                    (sm.tu[j] == sm.tu[best] && sm.idx[sm.ti[j]] < sm.idx[sm.ti[best]])) best = j;
            unsigned tub = sm.tu[best]; sm.tu[best] = sm.tu[a]; sm.tu[a] = tub;
            int tib = sm.ti[best]; sm.ti[best] = sm.ti[a]; sm.ti[a] = tib;
            sm.sel[nd + a] = sm.ti[a];
        }
    }
    __syncthreads();
}

// ---- 3x3 symmetric eigensolve (Jacobi, double) ----
__device__ void eig3(const float cf[6], double lam_out[3], double dir_out[3]) {
    double a[3][3], v[3][3];
    a[0][0] = cf[0]; a[0][1] = cf[1]; a[0][2] = cf[2];
    a[1][0] = cf[1]; a[1][1] = cf[3]; a[1][2] = cf[4];
    a[2][0] = cf[2]; a[2][1] = cf[4]; a[2][2] = cf[5];
    for (int i = 0; i < 3; i++)
        for (int j = 0; j < 3; j++) v[i][j] = (i == j) ? 1.0 : 0.0;

    for (int sweep = 0; sweep < 12; sweep++) {
        double off = a[0][1] * a[0][1] + a[0][2] * a[0][2] + a[1][2] * a[1][2];
        if (off == 0.0) break;
        for (int p = 0; p < 2; p++) {
            for (int q = p + 1; q < 3; q++) {
                double apq = a[p][q];
                if (apq == 0.0) continue;
                double app = a[p][p], aqq = a[q][q];
                double theta = (aqq - app) / (2.0 * apq);
                double t = (theta >= 0.0 ? 1.0 : -1.0) /
                           (fabs(theta) + sqrt(theta * theta + 1.0));
                double c = 1.0 / sqrt(t * t + 1.0);
                double s = t * c;
                a[p][p] = app - t * apq;
                a[q][q] = aqq + t * apq;
                a[p][q] = 0.0; a[q][p] = 0.0;
                for (int r = 0; r < 3; r++) {
                    if (r == p || r == q) continue;
                    double arp = a[r][p], arq = a[r][q];
                    a[r][p] = c * arp - s * arq; a[p][r] = a[r][p];
                    a[r][q] = s * arp + c * arq; a[q][r] = a[r][q];
                }
                for (int r = 0; r < 3; r++) {
                    double vrp = v[r][p], vrq = v[r][q];
                    v[r][p] = c * vrp - s * vrq;
                    v[r][q] = s * vrp + c * vrq;
                }
            }
        }
    }
    double l0 = a[0][0], l1 = a[1][1], l2 = a[2][2];
    int i0 = 0, i1 = 1, i2 = 2;
    if (l0 > l1) { double t = l0; l0 = l1; l1 = t; int ti = i0; i0 = i1; i1 = ti; }
    if (l1 > l2) { double t = l1; l1 = l2; l2 = t; int ti = i1; i1 = i2; i2 = ti; }
    if (l0 > l1) { double t = l0; l0 = l1; l1 = t; int ti = i0; i0 = i1; i1 = ti; }
    lam_out[0] = l0; lam_out[1] = l1; lam_out[2] = l2;
    dir_out[0] = v[0][i2]; dir_out[1] = v[1][i2]; dir_out[2] = v[2][i2];
}

// One block per (batch, group). No mid-kernel cross-block sync (round-2 lesson:
// agent-scope fences before hot loops cause an L2 invalidation storm).
// Phase 0: exact 100-NN of strided center -> mean (q1).
// Phase 1: certified survivor reuse in LDS; fallback: exact full scan.
// Tail: cov; then release-only done-election; last block finalizes inline.
template<bool SOA>
__global__ __launch_bounds__(TPB)
void fused_knn_kernel(const float* __restrict__ pts,
                      const float* __restrict__ sx, const float* __restrict__ sy,
                      const float* __restrict__ sz,
                      float* __restrict__ gmeans, float* __restrict__ covs,
                      float* __restrict__ out,
                      unsigned* __restrict__ syncw,   // [0] = done counter
                      int B, int nblk) {
    __shared__ KSmem sm;
    __shared__ int s_fastok;
    __shared__ int s_last;

    const int blk = blockIdx.x;
    const int b = blk % B;           // batch-per-XCD swizzle (L2 locality)
    const int g = blk / B;
    const int gi = b * G_NUMS + g;   // b-major for finalize
    const float* __restrict__ P = pts + (size_t)b * (N_PTS * 3);
    const float4* __restrict__ P4 = (const float4*)P;
    const float4* X4 = nullptr; const float4* Y4 = nullptr; const float4* Z4 = nullptr;
    if constexpr (SOA) {
        X4 = (const float4*)(sx + (size_t)b * N_PTS);
        Y4 = (const float4*)(sy + (size_t)b * N_PTS);
        Z4 = (const float4*)(sz + (size_t)b * N_PTS);
    }
    const int tid = threadIdx.x;
    const int lane = tid & 63, wid = tid >> 6;

    if (tid == 0) {
        const float* qp = P + (size_t)g * PT_STRIDE * 3;
        sm.q[0] = qp[0]; sm.q[1] = qp[1]; sm.q[2] = qp[2];
    }
    if (tid < 3) sm.acc[tid] = 0.f;
    if (tid < 6) sm.cov[tid] = 0.f;
    __syncthreads();
    const float qx = sm.q[0], qy = sm.q[1], qz = sm.q[2];

    // ================= phase 0 =================
    knn_select<SOA>(P4, X4, Y4, Z4, sm, qx, qy, qz, tid, lane, wid, true);

    if (tid < G_SIZE) {
        int p = sm.sel[tid];
        atomicAdd(&sm.acc[0], sm.px[p]);
        atomicAdd(&sm.acc[1], sm.py[p]);
        atomicAdd(&sm.acc[2], sm.pz[p]);
    }
    __syncthreads();
    const int S0 = sm.ns;            // raw phase-0 survivor count
    if (tid == 0) {
        float mx = sm.acc[0] * (1.0f / G_SIZE);
        float my = sm.acc[1] * (1.0f / G_SIZE);
        float mz = sm.acc[2] * (1.0f / G_SIZE);
        gmeans[(size_t)gi * 3 + 0] = mx;
        gmeans[(size_t)gi * 3 + 1] = my;
        gmeans[(size_t)gi * 3 + 2] = mz;
        float dx = mx - qx, dy = my - qy, dz = mz - qz;
        sm.delta2 = fmaf(dx, dx, fmaf(dy, dy, dz * dz));
        sm.q[0] = mx; sm.q[1] = my; sm.q[2] = mz;
        sm.acc[0] = 0.f; sm.acc[1] = 0.f; sm.acc[2] = 0.f;
        sm.maxu = 0u; sm.r1 = 0u; sm.T = 0u;
        sm.nd = 0; sm.nt = 0;
        s_last = 0;
        s_fastok = 0;
    }
    __syncthreads();
    const float q1x = sm.q[0], q1y = sm.q[1], q1z = sm.q[2];

    // ============ phase 1 fast path: certified survivor reuse (LDS coords) ============
    const bool attempt = (S0 >= G_SIZE) && (S0 <= CAP);  // complete survivor set
    if (attempt) {
        for (int j = tid; j < BINS; j += TPB) sm.hist[j] = 0u;
        for (int i = tid; i < S0; i += TPB) {
            unsigned uu = __float_as_uint(
                dist2f(sm.px[i], sm.py[i], sm.pz[i], q1x, q1y, q1z));
            sm.u[i] = uu;
            atomicMax(&sm.maxu, uu);
        }
        __syncthreads();
        unsigned maxu = sm.maxu;
        unsigned hb = (maxu == 0u) ? 0u : (32u - (unsigned)__clz(maxu));
        unsigned s3 = hb > 12u ? hb - 12u : 0u;
        for (int i = tid; i < S0; i += TPB) atomicAdd(&sm.hist[sm.u[i] >> s3], 1u);
        __syncthreads();
        unsigned T2 = find_bin(sm, G_SIZE, tid, lane, wid);
        const unsigned lo = T2 << s3;
        for (int i = tid; i < S0; i += TPB) {
            unsigned uu = sm.u[i];
            if (uu < lo) {
                int p = atomicAdd(&sm.nd, 1);
                if (p < G_SIZE) sm.sel[p] = i;
            } else if ((uu >> s3) == T2) {
                int p = atomicAdd(&sm.nt, 1);
                if (p < TIE_CAP) { sm.tu[p] = uu; sm.ti[p] = i; }
            }
        }
        __syncthreads();
        if (tid == 0) {
            int ok = 1;
            int nd = sm.nd; if (nd > G_SIZE) { nd = G_SIZE; ok = 0; }
            int need = G_SIZE - nd;
            if (sm.nt > TIE_CAP) ok = 0;
            int ec = sm.nt; if (ec > TIE_CAP) ec = TIE_CAP;
            if (need > ec) ok = 0;
            for (int a = 0; a < need && a < ec; ++a) {
                int best = a;
                for (int j = a + 1; j < ec; ++j)
                    if (sm.tu[j] < sm.tu[best] ||
                        (sm.tu[j] == sm.tu[best] && sm.idx[sm.ti[j]] < sm.idx[sm.ti[best]])) best = j;
                unsigned tub = sm.tu[best]; sm.tu[best] = sm.tu[a]; sm.tu[a] = tub;
                int tib = sm.ti[best]; sm.ti[best] = sm.ti[a]; sm.ti[a] = tib;
                sm.sel[nd + a] = sm.ti[a];
            }
            s_fastok = ok;
        }
        __syncthreads();
        if (s_fastok) {
            if (tid < G_SIZE) atomicMax(&sm.r1, sm.u[sm.sel[tid]]);
            __syncthreads();
            if (tid == 0) {
                // certificate: every non-survivor p has d0(p) >= R0, so
                // d1(p) >= R0 - delta; exact iff R0 - delta > r1 (with fp margin)
                double R0 = sqrt((double)__uint_as_float(sm.tau0));
                double dl = sqrt((double)sm.delta2);
                double r1 = sqrt((double)__uint_as_float(sm.r1));
                if (!((R0 - dl) > r1 * 1.0001 + 1e-7)) s_fastok = 0;
            }
            __syncthreads();
        }
    }

    // ============ phase 1 fallback: exact full scan (rare) ============
    if (!attempt || !s_fastok) {
        knn_select<SOA>(P4, X4, Y4, Z4, sm, q1x, q1y, q1z, tid, lane, wid, false);
    }

    // ============ mean / covariance over the exact 100 (LDS coords) ============
    float px = 0.f, py = 0.f, pz = 0.f;
    if (tid < G_SIZE) {
        int p = sm.sel[tid];
        px = sm.px[p]; py = sm.py[p]; pz = sm.pz[p];
        atomicAdd(&sm.acc[0], px);
        atomicAdd(&sm.acc[1], py);
        atomicAdd(&sm.acc[2], pz);
    }
    __syncthreads();
    float mx = sm.acc[0] * (1.0f / G_SIZE);
    float my = sm.acc[1] * (1.0f / G_SIZE);
    float mz = sm.acc[2] * (1.0f / G_SIZE);
    if (tid < G_SIZE) {
        float x = px - mx, y = py - my, z = pz - mz;
        atomicAdd(&sm.cov[0], x * x);
        atomicAdd(&sm.cov[1], x * y);
        atomicAdd(&sm.cov[2], x * z);
        atomicAdd(&sm.cov[3], y * y);
        atomicAdd(&sm.cov[4], y * z);
        atomicAdd(&sm.cov[5], z * z);
    }
    __syncthreads();
    if (tid < 6) covs[(size_t)gi * 6 + tid] = sm.cov[tid] * (1.0f / G_SIZE);

    // ============ last-block-done election (release-only; after ALL heavy work) ============
    __syncthreads();                 // all stores issued (barrier drains vmcnt)
    if (tid == 0) {
        unsigned old = __hip_atomic_fetch_add(&syncw[0], 1u, __ATOMIC_RELEASE,
                                              __HIP_MEMORY_SCOPE_AGENT);
        s_last = (old == (unsigned)(nblk - 1)) ? 1 : 0;
    }
    __syncthreads();
    if (!s_last) return;

    // ============ finalize (runs once, in the last block) ============
    // single acquire (one L2 invalidate, one block) to see all blocks' outputs
    (void)__hip_atomic_load(&syncw[0], __ATOMIC_ACQUIRE, __HIP_MEMORY_SCOPE_AGENT);
    const int NG = nblk;             // 240
    float et = 0.f;
    if (tid < NG) {
        float cf[6];
#pragma unroll
        for (int j = 0; j < 6; j++) cf[j] = covs[tid * 6 + j];
        double lam[3], dir[3];
        eig3(cf, lam, dir);
        double denom = lam[0] + lam[1] + lam[2] + 1e-9;
        et = (float)((lam[2] - lam[1]) / denom);
        sm.fin.dir[tid][0] = (float)dir[0];
        sm.fin.dir[tid][1] = (float)dir[1];
        sm.fin.dir[tid][2] = (float)dir[2];
        sm.fin.gm[tid][0] = gmeans[tid * 3 + 0];
        sm.fin.gm[tid][1] = gmeans[tid * 3 + 1];
        sm.fin.gm[tid][2] = gmeans[tid * 3 + 2];
    }
    __syncthreads();

    float st = 0.f;
    if (tid < NG) {
        int bb = tid / G_NUMS, gg0 = tid % G_NUMS;
        float gx = sm.fin.gm[tid][0], gy = sm.fin.gm[tid][1], gz = sm.fin.gm[tid][2];
        float bd = 3.4e38f; int bj = 0;
        for (int gg = 0; gg < G_NUMS; gg++) {
            if (gg == gg0) continue;
            int o = bb * G_NUMS + gg;
            float dx = gx - sm.fin.gm[o][0];
            float dy = gy - sm.fin.gm[o][1];
            float dz = gz - sm.fin.gm[o][2];
            float d = dx * dx + dy * dy + dz * dz;
            if (d < bd) { bd = d; bj = gg; }
        }
        int o = bb * G_NUMS + bj;
        float cosv = sm.fin.dir[tid][0] * sm.fin.dir[o][0] +
                     sm.fin.dir[tid][1] * sm.fin.dir[o][1] +
                     sm.fin.dir[tid][2] * sm.fin.dir[o][2];
        st = 1.f - cosv * cosv;
    }

    float e = et, s2 = st;
#pragma unroll
    for (int off = 32; off > 0; off >>= 1) {
        e += __shfl_down(e, off);
        s2 += __shfl_down(s2, off);
    }
    if (lane == 0) { sm.fin.pe[wid] = e; sm.fin.ps[wid] = s2; }
    __syncthreads();
    if (tid == 0) {
        float se = 0.f, ss = 0.f;
        for (int w = 0; w < NWAVES; w++) { se += sm.fin.pe[w]; ss += sm.fin.ps[w]; }
        out[0] = -se / (float)B + ss / (float)NG;
    }
}

// AoS -> SoA transpose: point k of batch b lands at [b*N + k] in each of sx/sy/sz.
__global__ __launch_bounds__(256)
void transpose_kernel(const float* __restrict__ pts,
                      float* __restrict__ sx, float* __restrict__ sy,
                      float* __restrict__ sz, int total4) {
    int t = blockIdx.x * 256 + threadIdx.x;
    if (t >= total4) return;
    const float4* __restrict__ P4 = (const float4*)pts;
    float4 f0 = P4[3 * t + 0];
    float4 f1 = P4[3 * t + 1];
    float4 f2 = P4[3 * t + 2];
    ((float4*)sx)[t] = make_float4(f0.x, f0.w, f1.z, f2.y);
    ((float4*)sy)[t] = make_float4(f0.y, f1.x, f1.w, f2.z);
    ((float4*)sz)[t] = make_float4(f0.z, f1.y, f2.x, f2.w);
}

extern "C" void kernel_launch(void* const* d_in, const int* in_sizes, int n_in,
                              void* d_out, int out_size, void* d_ws, size_t ws_size,
                              hipStream_t stream) {
    const float* pts = (const float*)d_in[0];
    float* out = (float*)d_out;
    float* ws = (float*)d_ws;
    int B = in_sizes[0] / (N_PTS * 3);   // 8
    int nblk = B * G_NUMS;               // 240

    float* gmeans = ws;                              // B*G_NUMS*3 floats
    float* covs = ws + (size_t)B * G_NUMS * 3;       // B*G_NUMS*6 floats
    const size_t base_floats = (size_t)B * G_NUMS * 9;
    unsigned* syncw = (unsigned*)(ws + base_floats); // 16 uints (done counter)
    float* soa = ws + base_floats + 16;
    const size_t soa_floats = 3 * (size_t)B * N_PTS;
    const bool use_soa = ws_size >= (base_floats + 16 + soa_floats) * sizeof(float);

    hipMemsetAsync(syncw, 0, 64, stream);            // zero done counter

    dim3 grid(nblk);
    if (use_soa) {
        float* sx = soa;
        float* sy = sx + (size_t)B * N_PTS;
        float* sz = sy + (size_t)B * N_PTS;
        int total4 = B * N_PTS / 4;
        transpose_kernel<<<dim3((total4 + 255) / 256), dim3(256), 0, stream>>>(
            pts, sx, sy, sz, total4);
        fused_knn_kernel<true><<<grid, TPB, 0, stream>>>(
            pts, sx, sy, sz, gmeans, covs, out, syncw, B, nblk);
    } else {
        fused_knn_kernel<false><<<grid, TPB, 0, stream>>>(
            pts, nullptr, nullptr, nullptr, gmeans, covs, out, syncw, B, nblk);
    }
}